// Round 25
// baseline (107.057 us; speedup 1.0000x reference)
//
#include <hip/hip_runtime.h>

#define NN 100000
#define NE 1600000
#define D 64
#define NR 8
#define TS 16                  // dst-tile size (nodes per block)
#define NT (NN / TS)           // 6250 tiles, exact
#define APK 36                 // packed accum row stride (dwords): 32 data + 4 pad
#define RPAD 17                // reduction scratch pad (floats)
#define NB 128                 // (r, dst&15) bins per tile
#define CAP 512                // slots per tile segment
#define CSTRIDE 16             // cursor padding: 1 cursor per 64B line
#define BK 250                 // coarse buckets (25 tiles = 400 nodes each)
#define BKCAP 8192             // slots per bucket segment (mean 6400, +22 sigma)
#define P1CHUNK 4096           // edges per pass-1 block (16/thread)
#define P1B ((NE + P1CHUNK - 1) / P1CHUNK)  // 391
#define P2CHUNK 2048           // edges per pass-2 block chunk
#define NWPK 4096              // W bf16-frag entries (8r x 2ks x 4g x 64col)
#define NWPKR 512              // Wr entries (2ks x 4g x 64col)
#define XPB 12500              // xpack blocks (NN*D/2 / 256)
#define PPB 18                 // prepack blocks

typedef short bf16x8 __attribute__((ext_vector_type(8)));
typedef float f32x4 __attribute__((ext_vector_type(4)));

// f32 -> bf16 round-to-nearest-even (finite inputs only)
__device__ __forceinline__ unsigned f2bfu(float f) {
    unsigned u = __float_as_uint(f);
    return (u + 0x7fffu + ((u >> 16) & 1u)) >> 16;
}
__device__ __forceinline__ unsigned pk2(float a, float b) {
    return (f2bfu(a) & 0xffffu) | (f2bfu(b) << 16);
}

__global__ void init_kernel(int* __restrict__ cursor, int* __restrict__ bkCursor) {
    int i = blockIdx.x * blockDim.x + threadIdx.x;
    if (i < NT) cursor[(size_t)i * CSTRIDE] = i * CAP;
    if (i < BK) bkCursor[(size_t)i * CSTRIDE] = 0;
}

// Combo dispatch: [0,P1B) radix pass 1 | [P1B,+XPB) xpack | [+PPB) prepack.
__global__ void __launch_bounds__(256) combo_kernel(
    const int* __restrict__ ei, const int* __restrict__ et,
    const float* __restrict__ x, const float* __restrict__ W,
    const float* __restrict__ Wr, int* __restrict__ bkCursor,
    int* __restrict__ bkSeg, unsigned* __restrict__ xb,
    uint4* __restrict__ wpk)
{
    __shared__ int eseq[P1CHUNK];
    __shared__ unsigned char ebk[P1CHUNK];
    __shared__ int bh[BK], bst[BK], bcur[BK], gbase[BK];
    const int blk = blockIdx.x;
    const int tid = threadIdx.x;

    if (blk >= P1B) {
        int b2 = blk - P1B;
        if (b2 < XPB) {
            int i = b2 * 256 + tid;            // < NN*D/2 exactly
            float2 f = ((const float2*)x)[i];
            xb[i] = pk2(f.x, f.y);
        } else {
            int e = (b2 - XPB) * 256 + tid;
            if (e >= NWPK + NWPKR) return;
            const float* src;
            int col, row0;
            if (e < NWPK) {
                int r = e >> 9, ks = (e >> 8) & 1, g = (e >> 6) & 3;
                col = e & 63;
                src = W + (size_t)r * D * D;
                row0 = ks * 32 + g * 8;
            } else {
                int e2 = e - NWPK;
                int ks = (e2 >> 8) & 1, g = (e2 >> 6) & 3;
                col = e2 & 63;
                src = Wr;
                row0 = ks * 32 + g * 8;
            }
            float v[8];
#pragma unroll
            for (int j = 0; j < 8; ++j) v[j] = src[(size_t)(row0 + j) * D + col];
            uint4 o;
            o.x = pk2(v[0], v[1]); o.y = pk2(v[2], v[3]);
            o.z = pk2(v[4], v[5]); o.w = pk2(v[6], v[7]);
            wpk[e] = o;
        }
        return;
    }

    // ---- radix pass 1: partition into 250 coarse buckets ----
    const int lane = tid & 63;
    const int wv = tid >> 6;
    const int c0 = blk * P1CHUNK;
    const int n = min(P1CHUNK, NE - c0);

    for (int i = tid; i < BK; i += 256) bh[i] = 0;
    __syncthreads();

    int rec[16], bkk[16];
#pragma unroll
    for (int k = 0; k < 16; ++k) {
        int e = c0 + tid + k * 256;
        bool ok = e < NE;
        int d = ok ? ei[NE + e] : 0;
        int s = ok ? ei[e] : 0;
        int r = ok ? et[e] : 0;
        unsigned bu = (unsigned)d / 400u;
        int dl = d - (int)bu * 400;
        rec[k] = s | (r << 17) | (dl << 20);
        bkk[k] = ok ? (int)bu : -1;
        if (ok) atomicAdd(&bh[bu], 1);
    }
    __syncthreads();
    if (wv == 0) {                  // 250-bin exclusive scan: 4 bins/lane
        int idx = lane * 4;
        int b0 = (idx + 0 < BK) ? bh[idx + 0] : 0;
        int b1 = (idx + 1 < BK) ? bh[idx + 1] : 0;
        int b2 = (idx + 2 < BK) ? bh[idx + 2] : 0;
        int b3 = (idx + 3 < BK) ? bh[idx + 3] : 0;
        int s = b0 + b1 + b2 + b3;
        int inc = s;
#pragma unroll
        for (int off = 1; off < 64; off <<= 1) {
            int u = __shfl_up(inc, off);
            if (lane >= off) inc += u;
        }
        int ex = inc - s;
        if (idx + 0 < BK) { bst[idx + 0] = ex; bcur[idx + 0] = ex; } ex += b0;
        if (idx + 1 < BK) { bst[idx + 1] = ex; bcur[idx + 1] = ex; } ex += b1;
        if (idx + 2 < BK) { bst[idx + 2] = ex; bcur[idx + 2] = ex; } ex += b2;
        if (idx + 3 < BK) { bst[idx + 3] = ex; bcur[idx + 3] = ex; }
    }
    __syncthreads();
#pragma unroll
    for (int k = 0; k < 16; ++k) {
        if (bkk[k] >= 0) {
            int p = atomicAdd(&bcur[bkk[k]], 1);
            eseq[p] = rec[k];
            ebk[p] = (unsigned char)bkk[k];
        }
    }
    __syncthreads();
    for (int i = tid; i < BK; i += 256) {
        int h = bh[i];
        gbase[i] = h ? atomicAdd(&bkCursor[(size_t)i * CSTRIDE], h) : 0;
    }
    __syncthreads();
#pragma unroll
    for (int k = 0; k < 16; ++k) {
        int j = tid + k * 256;
        if (j < n) {
            int bb = ebk[j];
            int pos = gbase[bb] + (j - bst[bb]);
            if (pos < BKCAP) bkSeg[(size_t)bb * BKCAP + pos] = eseq[j];
        }
    }
}

// Pass 2: per (bucket, chunk): coalesced read of bucket segment, 25-bin LDS
// sort by tile-local dst, 25 claim atomics, burst writes into sorted[].
__global__ void __launch_bounds__(256) p2_kernel(
    const int* __restrict__ bkCursor, const int* __restrict__ bkSeg,
    int* __restrict__ cursor, int* __restrict__ sorted)
{
    const int b = blockIdx.x >> 2;
    const int c = blockIdx.x & 3;
    int nb = bkCursor[(size_t)b * CSTRIDE];
    if (nb > BKCAP) nb = BKCAP;
    const int lo = c * P2CHUNK;
    if (lo >= nb) return;               // uniform across block
    const int hi = min(lo + P2CHUNK, nb);
    const int cnt = hi - lo;

    __shared__ int eseq2[P2CHUNK];
    __shared__ unsigned char etl[P2CHUNK];
    __shared__ int bh2[25], bst2[25], bcur2[25], gb2[25];
    const int tid = threadIdx.x;
    const int lane = tid & 63;
    const int wv = tid >> 6;

    if (tid < 25) bh2[tid] = 0;
    __syncthreads();

    int rec2[8], tl[8];
#pragma unroll
    for (int k = 0; k < 8; ++k) {
        int j = lo + tid + k * 256;
        bool ok = j < hi;
        int rv = ok ? bkSeg[(size_t)b * BKCAP + j] : 0;
        int dl = (rv >> 20) & 0x1FF;
        tl[k] = ok ? (dl >> 4) : -1;
        rec2[k] = (rv & 0xFFFFF) | ((dl & 15) << 20);
        if (ok) atomicAdd(&bh2[tl[k]], 1);
    }
    __syncthreads();
    if (wv == 0 && lane < 32) {         // 25-bin scan + per-tile claims
        int v = (lane < 25) ? bh2[lane] : 0;
        int inc = v;
#pragma unroll
        for (int off = 1; off < 32; off <<= 1) {
            int u = __shfl_up(inc, off);
            if (lane >= off) inc += u;
        }
        if (lane < 25) {
            int ex = inc - v;
            bst2[lane] = ex; bcur2[lane] = ex;
            int t = b * 25 + lane;
            gb2[lane] = v ? atomicAdd(&cursor[(size_t)t * CSTRIDE], v) : 0;
        }
    }
    __syncthreads();
#pragma unroll
    for (int k = 0; k < 8; ++k) {
        if (tl[k] >= 0) {
            int p = atomicAdd(&bcur2[tl[k]], 1);
            eseq2[p] = rec2[k];
            etl[p] = (unsigned char)tl[k];
        }
    }
    __syncthreads();
#pragma unroll
    for (int k = 0; k < 8; ++k) {
        int j = tid + k * 256;
        if (j < cnt) {
            int t5 = etl[j];
            int t = b * 25 + t5;
            int pos = gb2[t5] + (j - bst2[t5]);
            if (pos < t * CAP + CAP) sorted[pos] = eseq2[j];
        }
    }
}

// One block (8 waves, 512 thr) per dst-tile. Single-pass (csz<=512):
// Stage 1: in-LDS counting sort by bin=(r*16+t), wave-0 shfl prefix scan.
// Stage 2: 64 groups of 8 lanes; each group walks its TWO owned bins in
//          lockstep (2 independent gather chains). Lane loads uint4 (8 dims),
//          f32 accumulate; flush = mean-scale + bf16 pack.
// Stage 3: MFMA (A from packed LDS rows, B from wpk, root A from xb).
__global__ void __launch_bounds__(512) fused_kernel(
    const unsigned* __restrict__ xb, const int* __restrict__ sorted,
    const int* __restrict__ cursor, const uint4* __restrict__ wpk,
    const float* __restrict__ bias, float* __restrict__ out)
{
    __shared__ unsigned accum[NB * APK];   // packed bf16 rows, bin=r*16+t
    __shared__ int eseq[CAP];
    __shared__ int bh[NB], bst[NB], bcur[NB];
    const int tid = threadIdx.x;
    const int lane = tid & 63;
    const int wv = tid >> 6;          // 0..7
    const int tile = blockIdx.x;

    int csz = cursor[(size_t)tile * CSTRIDE] - tile * CAP;  // issued early
    if (tid < NB) bh[tid] = 0;
    __syncthreads();

    if (csz > CAP) csz = CAP;
    int rec = 0, bin = 0;
    const bool have = tid < csz;
    if (have) {
        rec = sorted[tile * CAP + tid];
        bin = ((rec >> 17) & 7) * 16 + ((rec >> 20) & 15);
        atomicAdd(&bh[bin], 1);
    }
    __syncthreads();
    if (wv == 0) {                     // parallel 128-bin exclusive scan
        int b0 = bh[2 * lane], b1 = bh[2 * lane + 1];
        int s = b0 + b1;
        int inc = s;
#pragma unroll
        for (int off = 1; off < 64; off <<= 1) {
            int u = __shfl_up(inc, off);
            if (lane >= off) inc += u;
        }
        int excl = inc - s;
        bst[2 * lane] = excl;          bcur[2 * lane] = excl;
        bst[2 * lane + 1] = excl + b0; bcur[2 * lane + 1] = excl + b0;
    }
    __syncthreads();
    if (have) {
        int p = atomicAdd(&bcur[bin], 1);
        eseq[p] = rec;
    }
    __syncthreads();
    {
        const int grp8 = tid >> 3;     // 0..63
        const int q8 = tid & 7;        // uint4 slot in row (8 dims)
        const int bbA = grp8;          // owned bin 0
        const int bbB = grp8 + 64;     // owned bin 1
        const int mA = bh[bbA], mB = bh[bbB];
        const int stA = bst[bbA], stB = bst[bbB];
        float x0=0.f,x1=0.f,x2=0.f,x3=0.f,x4=0.f,x5=0.f,x6=0.f,x7=0.f;
        float y0=0.f,y1=0.f,y2=0.f,y3=0.f,y4=0.f,y5=0.f,y6=0.f,y7=0.f;
        const int mm = max(mA, mB);
        for (int i = 0; i < mm; ++i) {      // 2 independent gather chains
            if (i < mA) {
                int s = eseq[stA + i] & 0x1FFFF;
                uint4 v = *(const uint4*)(xb + (size_t)s * (D / 2) + q8 * 4);
                x0 += __uint_as_float(v.x << 16);
                x1 += __uint_as_float(v.x & 0xffff0000u);
                x2 += __uint_as_float(v.y << 16);
                x3 += __uint_as_float(v.y & 0xffff0000u);
                x4 += __uint_as_float(v.z << 16);
                x5 += __uint_as_float(v.z & 0xffff0000u);
                x6 += __uint_as_float(v.w << 16);
                x7 += __uint_as_float(v.w & 0xffff0000u);
            }
            if (i < mB) {
                int s = eseq[stB + i] & 0x1FFFF;
                uint4 v = *(const uint4*)(xb + (size_t)s * (D / 2) + q8 * 4);
                y0 += __uint_as_float(v.x << 16);
                y1 += __uint_as_float(v.x & 0xffff0000u);
                y2 += __uint_as_float(v.y << 16);
                y3 += __uint_as_float(v.y & 0xffff0000u);
                y4 += __uint_as_float(v.z << 16);
                y5 += __uint_as_float(v.z & 0xffff0000u);
                y6 += __uint_as_float(v.w << 16);
                y7 += __uint_as_float(v.w & 0xffff0000u);
            }
        }
        float scA = 1.0f / fmaxf((float)mA, 1.0f);
        float scB = 1.0f / fmaxf((float)mB, 1.0f);
        uint4 oA, oB;
        oA.x = pk2(x0 * scA, x1 * scA); oA.y = pk2(x2 * scA, x3 * scA);
        oA.z = pk2(x4 * scA, x5 * scA); oA.w = pk2(x6 * scA, x7 * scA);
        oB.x = pk2(y0 * scB, y1 * scB); oB.y = pk2(y2 * scB, y3 * scB);
        oB.z = pk2(y4 * scB, y5 * scB); oB.w = pk2(y6 * scB, y7 * scB);
        *(uint4*)(&accum[bbA * APK + q8 * 4]) = oA;   // group-owned writes
        *(uint4*)(&accum[bbB * APK + q8 * 4]) = oB;
    }
    __syncthreads();

    // Stage 3: MFMA. A: m=lane&15 (node), k=g*8+j (+32*ks); B from wpk.
    // C/D: col=lane&15, row=(lane>>4)*4+i.
    const int ncol = lane & 15;
    const int g = lane >> 4;
    const int h = wv >> 2;            // relation half
    const int slice = wv & 3;         // output col slice (16 cols)
    f32x4 acc = {0.0f, 0.0f, 0.0f, 0.0f};

#pragma unroll
    for (int rr = 0; rr < 4; ++rr) {
        const int r = h * 4 + rr;
        const int bb = r * TS + ncol;
#pragma unroll
        for (int ks = 0; ks < 2; ++ks) {
            uint4 a4 = *(const uint4*)(accum + bb * APK + ks * 16 + g * 4);
            uint4 b4 = wpk[((r * 2 + ks) * 4 + g) * 64 + slice * 16 + ncol];
            bf16x8 af = __builtin_bit_cast(bf16x8, a4);
            bf16x8 bf = __builtin_bit_cast(bf16x8, b4);
            acc = __builtin_amdgcn_mfma_f32_16x16x32_bf16(af, bf, acc, 0, 0, 0);
        }
    }
    if (h == 0) {  // root transform: A-frags straight from packed xb
        const unsigned* xr = xb + (size_t)(tile * TS + ncol) * (D / 2);
#pragma unroll
        for (int ks = 0; ks < 2; ++ks) {
            uint4 a4 = *(const uint4*)(xr + ks * 16 + g * 4);
            bf16x8 af = __builtin_bit_cast(bf16x8, a4);
            uint4 b4 = wpk[NWPK + (ks * 4 + g) * 64 + slice * 16 + ncol];
            bf16x8 bf = __builtin_bit_cast(bf16x8, b4);
            acc = __builtin_amdgcn_mfma_f32_16x16x32_bf16(af, bf, acc, 0, 0, 0);
        }
    }
    __syncthreads();                   // all accum reads done
    float* red = (float*)accum;        // alias reuse for cross-half reduction
    const int rrow = g * 4;
    if (h == 1) {
#pragma unroll
        for (int i = 0; i < 4; ++i)
            red[(slice * 16 + rrow + i) * RPAD + ncol] = acc[i];
    }
    __syncthreads();
    if (h == 0) {
        const float bv = bias[slice * 16 + ncol];
#pragma unroll
        for (int i = 0; i < 4; ++i) {
            float v = acc[i] + red[(slice * 16 + rrow + i) * RPAD + ncol] + bv;
            v = fmaxf(v, 0.0f);
            out[((size_t)tile * TS + rrow + i) * D + slice * 16 + ncol] = v;
        }
    }
}

extern "C" void kernel_launch(void* const* d_in, const int* in_sizes, int n_in,
                              void* d_out, int out_size, void* d_ws, size_t ws_size,
                              hipStream_t stream) {
    const float* x    = (const float*)d_in[0];
    const int*   ei   = (const int*)d_in[1];   // [2, NE]
    const int*   et   = (const int*)d_in[2];   // [NE]
    const float* W    = (const float*)d_in[3]; // [NR, D, D]
    const float* Wr   = (const float*)d_in[4]; // [D, D]
    const float* bias = (const float*)d_in[5]; // [D]
    float* out = (float*)d_out;                // [NN, D]

    // ws layout (ints, 16B-aligned blocks): cursor[NT*16] | bkCursor[BK*16] |
    // sorted[NT*CAP] | bkSeg[BK*BKCAP] | xb[NN*32] | wpk[(NWPK+NWPKR)*uint4]
    int* cursor = (int*)d_ws;
    size_t o1 = (size_t)NT * CSTRIDE;
    int* bkCursor = cursor + o1;
    size_t o2 = o1 + (size_t)BK * CSTRIDE;
    int* sorted = cursor + o2;
    size_t o3 = o2 + (size_t)NT * CAP;
    int* bkSeg = cursor + o3;
    size_t o4 = o3 + (size_t)BK * BKCAP;
    unsigned* xb = (unsigned*)(cursor + o4);
    size_t o5 = o4 + (size_t)NN * (D / 2);
    o5 = (o5 + 3) & ~(size_t)3;
    uint4* wpk = (uint4*)(cursor + o5);

    init_kernel<<<(NT + 255) / 256, 256, 0, stream>>>(cursor, bkCursor);
    combo_kernel<<<P1B + XPB + PPB, 256, 0, stream>>>(ei, et, x, W, Wr,
                                                      bkCursor, bkSeg, xb, wpk);
    p2_kernel<<<BK * 4, 256, 0, stream>>>(bkCursor, bkSeg, cursor, sorted);
    fused_kernel<<<NT, 512, 0, stream>>>(xb, sorted, cursor, wpk, bias, out);
}

// Round 26
// 99.878 us; speedup vs baseline: 1.0719x; 1.0719x over previous
//
#include <hip/hip_runtime.h>

#define NN 100000
#define NE 1600000
#define D 64
#define NR 8
#define TS 16                  // dst-tile size (nodes per block)
#define NT (NN / TS)           // 6250 tiles, exact
#define APK 36                 // packed accum row stride (dwords): 32 data + 4 pad
#define RPAD 17                // reduction scratch pad (floats)
#define NB 128                 // (r, dst&15) bins per tile
#define CAP 512                // slots per tile segment
#define CSTRIDE 16             // cursor padding: 1 cursor per 64B line
#define BK 250                 // coarse buckets (25 tiles = 400 nodes each)
#define BKCAP 8192             // slots per bucket segment (mean 6400, +22 sigma)
#define P1CHUNK 4096           // edges per pass-1 block (16/thread)
#define P1B ((NE + P1CHUNK - 1) / P1CHUNK)  // 391
#define P2CHUNK 2048           // edges per pass-2 block chunk
#define NWPK 4096              // W bf16-frag entries (8r x 2ks x 4g x 64col)
#define NWPKR 512              // Wr entries (2ks x 4g x 64col)
#define XPB 12500              // xpack blocks (NN*D/2 / 256)
#define PPB 18                 // prepack blocks

typedef short bf16x8 __attribute__((ext_vector_type(8)));
typedef float f32x4 __attribute__((ext_vector_type(4)));

// f32 -> bf16 round-to-nearest-even (finite inputs only)
__device__ __forceinline__ unsigned f2bfu(float f) {
    unsigned u = __float_as_uint(f);
    return (u + 0x7fffu + ((u >> 16) & 1u)) >> 16;
}
__device__ __forceinline__ unsigned pk2(float a, float b) {
    return (f2bfu(a) & 0xffffu) | (f2bfu(b) << 16);
}

__global__ void init_kernel(int* __restrict__ cursor, int* __restrict__ bkCursor) {
    int i = blockIdx.x * blockDim.x + threadIdx.x;
    if (i < NT) cursor[(size_t)i * CSTRIDE] = i * CAP;
    if (i < BK) bkCursor[(size_t)i * CSTRIDE] = 0;
}

// Combo dispatch: [0,P1B) radix pass 1 | [P1B,+XPB) xpack | [+PPB) prepack.
// p1 and setup are data-independent; one dispatch overlaps their traffic.
__global__ void __launch_bounds__(256) combo_kernel(
    const int* __restrict__ ei, const int* __restrict__ et,
    const float* __restrict__ x, const float* __restrict__ W,
    const float* __restrict__ Wr, int* __restrict__ bkCursor,
    int* __restrict__ bkSeg, unsigned* __restrict__ xb,
    uint4* __restrict__ wpk)
{
    __shared__ int eseq[P1CHUNK];
    __shared__ unsigned char ebk[P1CHUNK];
    __shared__ int bh[BK], bst[BK], bcur[BK], gbase[BK];
    const int blk = blockIdx.x;
    const int tid = threadIdx.x;

    if (blk >= P1B) {
        int b2 = blk - P1B;
        if (b2 < XPB) {
            int i = b2 * 256 + tid;            // < NN*D/2 exactly
            float2 f = ((const float2*)x)[i];
            xb[i] = pk2(f.x, f.y);
        } else {
            int e = (b2 - XPB) * 256 + tid;
            if (e >= NWPK + NWPKR) return;
            const float* src;
            int col, row0;
            if (e < NWPK) {
                int r = e >> 9, ks = (e >> 8) & 1, g = (e >> 6) & 3;
                col = e & 63;
                src = W + (size_t)r * D * D;
                row0 = ks * 32 + g * 8;
            } else {
                int e2 = e - NWPK;
                int ks = (e2 >> 8) & 1, g = (e2 >> 6) & 3;
                col = e2 & 63;
                src = Wr;
                row0 = ks * 32 + g * 8;
            }
            float v[8];
#pragma unroll
            for (int j = 0; j < 8; ++j) v[j] = src[(size_t)(row0 + j) * D + col];
            uint4 o;
            o.x = pk2(v[0], v[1]); o.y = pk2(v[2], v[3]);
            o.z = pk2(v[4], v[5]); o.w = pk2(v[6], v[7]);
            wpk[e] = o;
        }
        return;
    }

    // ---- radix pass 1: partition into 250 coarse buckets ----
    const int lane = tid & 63;
    const int wv = tid >> 6;
    const int c0 = blk * P1CHUNK;
    const int n = min(P1CHUNK, NE - c0);

    for (int i = tid; i < BK; i += 256) bh[i] = 0;
    __syncthreads();

    int rec[16], bkk[16];
#pragma unroll
    for (int k = 0; k < 16; ++k) {
        int e = c0 + tid + k * 256;
        bool ok = e < NE;
        int d = ok ? ei[NE + e] : 0;
        int s = ok ? ei[e] : 0;
        int r = ok ? et[e] : 0;
        unsigned bu = (unsigned)d / 400u;
        int dl = d - (int)bu * 400;
        rec[k] = s | (r << 17) | (dl << 20);
        bkk[k] = ok ? (int)bu : -1;
        if (ok) atomicAdd(&bh[bu], 1);
    }
    __syncthreads();
    if (wv == 0) {                  // 250-bin exclusive scan: 4 bins/lane
        int idx = lane * 4;
        int b0 = (idx + 0 < BK) ? bh[idx + 0] : 0;
        int b1 = (idx + 1 < BK) ? bh[idx + 1] : 0;
        int b2 = (idx + 2 < BK) ? bh[idx + 2] : 0;
        int b3 = (idx + 3 < BK) ? bh[idx + 3] : 0;
        int s = b0 + b1 + b2 + b3;
        int inc = s;
#pragma unroll
        for (int off = 1; off < 64; off <<= 1) {
            int u = __shfl_up(inc, off);
            if (lane >= off) inc += u;
        }
        int ex = inc - s;
        if (idx + 0 < BK) { bst[idx + 0] = ex; bcur[idx + 0] = ex; } ex += b0;
        if (idx + 1 < BK) { bst[idx + 1] = ex; bcur[idx + 1] = ex; } ex += b1;
        if (idx + 2 < BK) { bst[idx + 2] = ex; bcur[idx + 2] = ex; } ex += b2;
        if (idx + 3 < BK) { bst[idx + 3] = ex; bcur[idx + 3] = ex; }
    }
    __syncthreads();
#pragma unroll
    for (int k = 0; k < 16; ++k) {
        if (bkk[k] >= 0) {
            int p = atomicAdd(&bcur[bkk[k]], 1);
            eseq[p] = rec[k];
            ebk[p] = (unsigned char)bkk[k];
        }
    }
    __syncthreads();
    for (int i = tid; i < BK; i += 256) {
        int h = bh[i];
        gbase[i] = h ? atomicAdd(&bkCursor[(size_t)i * CSTRIDE], h) : 0;
    }
    __syncthreads();
#pragma unroll
    for (int k = 0; k < 16; ++k) {
        int j = tid + k * 256;
        if (j < n) {
            int bb = ebk[j];
            int pos = gbase[bb] + (j - bst[bb]);
            if (pos < BKCAP) bkSeg[(size_t)bb * BKCAP + pos] = eseq[j];
        }
    }
}

// Pass 2: per (bucket, chunk): coalesced read of bucket segment, 25-bin LDS
// sort by tile-local dst, 25 claim atomics, burst writes into sorted[].
__global__ void __launch_bounds__(256) p2_kernel(
    const int* __restrict__ bkCursor, const int* __restrict__ bkSeg,
    int* __restrict__ cursor, int* __restrict__ sorted)
{
    const int b = blockIdx.x >> 2;
    const int c = blockIdx.x & 3;
    int nb = bkCursor[(size_t)b * CSTRIDE];
    if (nb > BKCAP) nb = BKCAP;
    const int lo = c * P2CHUNK;
    if (lo >= nb) return;               // uniform across block
    const int hi = min(lo + P2CHUNK, nb);
    const int cnt = hi - lo;

    __shared__ int eseq2[P2CHUNK];
    __shared__ unsigned char etl[P2CHUNK];
    __shared__ int bh2[25], bst2[25], bcur2[25], gb2[25];
    const int tid = threadIdx.x;
    const int lane = tid & 63;
    const int wv = tid >> 6;

    if (tid < 25) bh2[tid] = 0;
    __syncthreads();

    int rec2[8], tl[8];
#pragma unroll
    for (int k = 0; k < 8; ++k) {
        int j = lo + tid + k * 256;
        bool ok = j < hi;
        int rv = ok ? bkSeg[(size_t)b * BKCAP + j] : 0;
        int dl = (rv >> 20) & 0x1FF;
        tl[k] = ok ? (dl >> 4) : -1;
        rec2[k] = (rv & 0xFFFFF) | ((dl & 15) << 20);
        if (ok) atomicAdd(&bh2[tl[k]], 1);
    }
    __syncthreads();
    if (wv == 0 && lane < 32) {         // 25-bin scan + per-tile claims
        int v = (lane < 25) ? bh2[lane] : 0;
        int inc = v;
#pragma unroll
        for (int off = 1; off < 32; off <<= 1) {
            int u = __shfl_up(inc, off);
            if (lane >= off) inc += u;
        }
        if (lane < 25) {
            int ex = inc - v;
            bst2[lane] = ex; bcur2[lane] = ex;
            int t = b * 25 + lane;
            gb2[lane] = v ? atomicAdd(&cursor[(size_t)t * CSTRIDE], v) : 0;
        }
    }
    __syncthreads();
#pragma unroll
    for (int k = 0; k < 8; ++k) {
        if (tl[k] >= 0) {
            int p = atomicAdd(&bcur2[tl[k]], 1);
            eseq2[p] = rec2[k];
            etl[p] = (unsigned char)tl[k];
        }
    }
    __syncthreads();
#pragma unroll
    for (int k = 0; k < 8; ++k) {
        int j = tid + k * 256;
        if (j < cnt) {
            int t5 = etl[j];
            int t = b * 25 + t5;
            int pos = gb2[t5] + (j - bst2[t5]);
            if (pos < t * CAP + CAP) sorted[pos] = eseq2[j];
        }
    }
}

// One block (8 waves, 512 thr) per dst-tile. Single-pass (csz<=512):
// Stage 1: in-LDS counting sort by bin=(r*16+t), wave-0 shfl prefix scan.
// Stage 2: 64 groups of 8 lanes; each group owns 2 bins (mean 4 edges),
//          walked serially 2-deep (measured optimum vs interleaves).
//          Lane loads uint4 (8 dims), f32 accumulate; flush = scale+pack.
// Stage 3: MFMA (A from packed LDS rows, B from wpk, root A prefetched).
__global__ void __launch_bounds__(512) fused_kernel(
    const unsigned* __restrict__ xb, const int* __restrict__ sorted,
    const int* __restrict__ cursor, const uint4* __restrict__ wpk,
    const float* __restrict__ bias, float* __restrict__ out)
{
    __shared__ unsigned accum[NB * APK];   // packed bf16 rows, bin=r*16+t
    __shared__ int eseq[CAP];
    __shared__ int bh[NB], bst[NB], bcur[NB];
    const int tid = threadIdx.x;
    const int lane = tid & 63;
    const int wv = tid >> 6;          // 0..7
    const int tile = blockIdx.x;

    int csz = cursor[(size_t)tile * CSTRIDE] - tile * CAP;  // issued early
    // prefetch root A-fragments (used by h==0 waves in stage 3)
    const unsigned* xr = xb + (size_t)(tile * TS + (lane & 15)) * (D / 2);
    const int gpre = lane >> 4;
    uint4 ra0 = *(const uint4*)(xr + 0 * 16 + gpre * 4);
    uint4 ra1 = *(const uint4*)(xr + 1 * 16 + gpre * 4);

    if (tid < NB) bh[tid] = 0;
    __syncthreads();

    if (csz > CAP) csz = CAP;
    int rec = 0, bin = 0;
    const bool have = tid < csz;
    if (have) {
        rec = sorted[tile * CAP + tid];
        bin = ((rec >> 17) & 7) * 16 + ((rec >> 20) & 15);
        atomicAdd(&bh[bin], 1);
    }
    __syncthreads();
    if (wv == 0) {                     // parallel 128-bin exclusive scan
        int b0 = bh[2 * lane], b1 = bh[2 * lane + 1];
        int s = b0 + b1;
        int inc = s;
#pragma unroll
        for (int off = 1; off < 64; off <<= 1) {
            int u = __shfl_up(inc, off);
            if (lane >= off) inc += u;
        }
        int excl = inc - s;
        bst[2 * lane] = excl;          bcur[2 * lane] = excl;
        bst[2 * lane + 1] = excl + b0; bcur[2 * lane + 1] = excl + b0;
    }
    __syncthreads();
    if (have) {
        int p = atomicAdd(&bcur[bin], 1);
        eseq[p] = rec;
    }
    __syncthreads();
    {
        const int grp8 = tid >> 3;     // 0..63
        const int q8 = tid & 7;        // uint4 slot in row (8 dims)
#pragma unroll
        for (int half = 0; half < 2; ++half) {
            const int bb = grp8 + half * 64;
            int m = bh[bb];
            int st = bst[bb];
            float a0=0.f,a1=0.f,a2=0.f,a3=0.f,a4=0.f,a5=0.f,a6=0.f,a7=0.f;
            int i = 0;
            for (; i + 1 < m; i += 2) {
                int s0 = eseq[st + i] & 0x1FFFF;
                int s1 = eseq[st + i + 1] & 0x1FFFF;
                uint4 v0 = *(const uint4*)(xb + (size_t)s0 * (D / 2) + q8 * 4);
                uint4 v1 = *(const uint4*)(xb + (size_t)s1 * (D / 2) + q8 * 4);
                a0 += __uint_as_float(v0.x << 16) + __uint_as_float(v1.x << 16);
                a1 += __uint_as_float(v0.x & 0xffff0000u) + __uint_as_float(v1.x & 0xffff0000u);
                a2 += __uint_as_float(v0.y << 16) + __uint_as_float(v1.y << 16);
                a3 += __uint_as_float(v0.y & 0xffff0000u) + __uint_as_float(v1.y & 0xffff0000u);
                a4 += __uint_as_float(v0.z << 16) + __uint_as_float(v1.z << 16);
                a5 += __uint_as_float(v0.z & 0xffff0000u) + __uint_as_float(v1.z & 0xffff0000u);
                a6 += __uint_as_float(v0.w << 16) + __uint_as_float(v1.w << 16);
                a7 += __uint_as_float(v0.w & 0xffff0000u) + __uint_as_float(v1.w & 0xffff0000u);
            }
            if (i < m) {
                int s0 = eseq[st + i] & 0x1FFFF;
                uint4 v0 = *(const uint4*)(xb + (size_t)s0 * (D / 2) + q8 * 4);
                a0 += __uint_as_float(v0.x << 16);
                a1 += __uint_as_float(v0.x & 0xffff0000u);
                a2 += __uint_as_float(v0.y << 16);
                a3 += __uint_as_float(v0.y & 0xffff0000u);
                a4 += __uint_as_float(v0.z << 16);
                a5 += __uint_as_float(v0.z & 0xffff0000u);
                a6 += __uint_as_float(v0.w << 16);
                a7 += __uint_as_float(v0.w & 0xffff0000u);
            }
            float sc = 1.0f / fmaxf((float)m, 1.0f);  // mean fold at flush
            uint4 o;
            o.x = pk2(a0 * sc, a1 * sc);
            o.y = pk2(a2 * sc, a3 * sc);
            o.z = pk2(a4 * sc, a5 * sc);
            o.w = pk2(a6 * sc, a7 * sc);
            *(uint4*)(&accum[bb * APK + q8 * 4]) = o;  // group-owned write
        }
    }
    __syncthreads();

    // Stage 3: MFMA. A: m=lane&15 (node), k=g*8+j (+32*ks); B from wpk.
    // C/D: col=lane&15, row=(lane>>4)*4+i.
    const int ncol = lane & 15;
    const int g = lane >> 4;
    const int h = wv >> 2;            // relation half
    const int slice = wv & 3;         // output col slice (16 cols)
    f32x4 acc = {0.0f, 0.0f, 0.0f, 0.0f};

#pragma unroll
    for (int rr = 0; rr < 4; ++rr) {
        const int r = h * 4 + rr;
        const int bb = r * TS + ncol;
#pragma unroll
        for (int ks = 0; ks < 2; ++ks) {
            uint4 a4 = *(const uint4*)(accum + bb * APK + ks * 16 + g * 4);
            uint4 b4 = wpk[((r * 2 + ks) * 4 + g) * 64 + slice * 16 + ncol];
            bf16x8 af = __builtin_bit_cast(bf16x8, a4);
            bf16x8 bf = __builtin_bit_cast(bf16x8, b4);
            acc = __builtin_amdgcn_mfma_f32_16x16x32_bf16(af, bf, acc, 0, 0, 0);
        }
    }
    if (h == 0) {  // root transform: prefetched A-frags
#pragma unroll
        for (int ks = 0; ks < 2; ++ks) {
            uint4 a4 = (ks == 0) ? ra0 : ra1;
            bf16x8 af = __builtin_bit_cast(bf16x8, a4);
            uint4 b4 = wpk[NWPK + (ks * 4 + g) * 64 + slice * 16 + ncol];
            bf16x8 bf = __builtin_bit_cast(bf16x8, b4);
            acc = __builtin_amdgcn_mfma_f32_16x16x32_bf16(af, bf, acc, 0, 0, 0);
        }
    }
    __syncthreads();                   // all accum reads done
    float* red = (float*)accum;        // alias reuse for cross-half reduction
    const int rrow = g * 4;
    if (h == 1) {
#pragma unroll
        for (int i = 0; i < 4; ++i)
            red[(slice * 16 + rrow + i) * RPAD + ncol] = acc[i];
    }
    __syncthreads();
    if (h == 0) {
        const float bv = bias[slice * 16 + ncol];
#pragma unroll
        for (int i = 0; i < 4; ++i) {
            float v = acc[i] + red[(slice * 16 + rrow + i) * RPAD + ncol] + bv;
            v = fmaxf(v, 0.0f);
            out[((size_t)tile * TS + rrow + i) * D + slice * 16 + ncol] = v;
        }
    }
}

extern "C" void kernel_launch(void* const* d_in, const int* in_sizes, int n_in,
                              void* d_out, int out_size, void* d_ws, size_t ws_size,
                              hipStream_t stream) {
    const float* x    = (const float*)d_in[0];
    const int*   ei   = (const int*)d_in[1];   // [2, NE]
    const int*   et   = (const int*)d_in[2];   // [NE]
    const float* W    = (const float*)d_in[3]; // [NR, D, D]
    const float* Wr   = (const float*)d_in[4]; // [D, D]
    const float* bias = (const float*)d_in[5]; // [D]
    float* out = (float*)d_out;                // [NN, D]

    // ws layout (ints, 16B-aligned blocks): cursor[NT*16] | bkCursor[BK*16] |
    // sorted[NT*CAP] | bkSeg[BK*BKCAP] | xb[NN*32] | wpk[(NWPK+NWPKR)*uint4]
    int* cursor = (int*)d_ws;
    size_t o1 = (size_t)NT * CSTRIDE;
    int* bkCursor = cursor + o1;
    size_t o2 = o1 + (size_t)BK * CSTRIDE;
    int* sorted = cursor + o2;
    size_t o3 = o2 + (size_t)NT * CAP;
    int* bkSeg = cursor + o3;
    size_t o4 = o3 + (size_t)BK * BKCAP;
    unsigned* xb = (unsigned*)(cursor + o4);
    size_t o5 = o4 + (size_t)NN * (D / 2);
    o5 = (o5 + 3) & ~(size_t)3;
    uint4* wpk = (uint4*)(cursor + o5);

    init_kernel<<<(NT + 255) / 256, 256, 0, stream>>>(cursor, bkCursor);
    combo_kernel<<<P1B + XPB + PPB, 256, 0, stream>>>(ei, et, x, W, Wr,
                                                      bkCursor, bkSeg, xb, wpk);
    p2_kernel<<<BK * 4, 256, 0, stream>>>(bkCursor, bkSeg, cursor, sorted);
    fused_kernel<<<NT, 512, 0, stream>>>(xb, sorted, cursor, wpk, bias, out);
}